// Round 3
// baseline (202.329 us; speedup 1.0000x reference)
//
#include <hip/hip_runtime.h>
#include <hip/hip_bf16.h>

// 24-qubit brickwork circuit, register-resident gates + pk_fma + float4 I/O.
// State: flat index i in [0, 2^24), wire w <-> bit (23-w).
// Gate on wires (w,w+1): p1 = 22-w, p0 = 23-w. M[v][u] = G[u0,v0,u1,v1].

typedef float v2f __attribute__((ext_vector_type(2)));

#define SWZ(j) ((j) ^ (((j) >> 6) & 15) ^ ((((j) >> 10) & 1) << 4))

// Gate on register bits (A, A+1) of a 64-amp register file.
// float2-vectorized so the backend emits v_pk_fma_f32 (f32 peak needs pk).
template<int A>
__device__ __forceinline__ void gate_regs(float v[64], const float* __restrict__ g) {
  float m[16];
#pragma unroll
  for (int vv = 0; vv < 4; ++vv)
#pragma unroll
    for (int uu = 0; uu < 4; ++uu)
      m[vv * 4 + uu] = g[(uu >> 1) * 8 + (vv >> 1) * 4 + (uu & 1) * 2 + (vv & 1)];
  if constexpr (A == 0) {
    // quads are consecutive; vectorize across the two output pairs
    v2f m04 = {m[0], m[4]}, m15 = {m[1], m[5]}, m26 = {m[2], m[6]}, m37 = {m[3], m[7]};
    v2f m8c = {m[8], m[12]}, m9d = {m[9], m[13]}, mae = {m[10], m[14]}, mbf = {m[11], m[15]};
#pragma unroll
    for (int q = 0; q < 16; ++q) {
      const float a0 = v[4 * q], a1 = v[4 * q + 1], a2 = v[4 * q + 2], a3 = v[4 * q + 3];
      v2f r01 = m04 * a0 + m15 * a1 + m26 * a2 + m37 * a3;
      v2f r23 = m8c * a0 + m9d * a1 + mae * a2 + mbf * a3;
      v[4 * q] = r01.x; v[4 * q + 1] = r01.y; v[4 * q + 2] = r23.x; v[4 * q + 3] = r23.y;
    }
  } else {
    // vectorize along register bit 0 (orthogonal to acting bits)
    constexpr int S = 1 << A;
#pragma unroll
    for (int hi = 0; hi < (1 << (4 - A)); ++hi)
#pragma unroll
      for (int lo2 = 0; lo2 < S / 2; ++lo2) {
        const int base = (hi << (A + 2)) | (lo2 << 1);
        v2f a0 = {v[base], v[base + 1]};
        v2f a1 = {v[base + S], v[base + S + 1]};
        v2f a2 = {v[base + 2 * S], v[base + 2 * S + 1]};
        v2f a3 = {v[base + 3 * S], v[base + 3 * S + 1]};
        v2f r0 = m[0] * a0 + m[1] * a1 + m[2] * a2 + m[3] * a3;
        v2f r1 = m[4] * a0 + m[5] * a1 + m[6] * a2 + m[7] * a3;
        v2f r2 = m[8] * a0 + m[9] * a1 + m[10] * a2 + m[11] * a3;
        v2f r3 = m[12] * a0 + m[13] * a1 + m[14] * a2 + m[15] * a3;
        v[base] = r0.x; v[base + 1] = r0.y;
        v[base + S] = r1.x; v[base + S + 1] = r1.y;
        v[base + 2 * S] = r2.x; v[base + 2 * S + 1] = r2.y;
        v[base + 3 * S] = r3.x; v[base + 3 * S + 1] = r3.y;
      }
  }
}

// register-window layouts (j = 14-bit tile index, t = thread, r = reg)
#define J_B(t, r)  (((r) << 8) | (t))                                  // r = j8..13
#define J_M(t, r)  ((((t) >> 4) << 10) | ((r) << 4) | ((t) & 15))      // r = j4..9
#define J_A(t, r)  (((t) << 6) | (r))                                  // r = j0..5
#define J_W(t, r)  ((((t) >> 5) << 11) | ((r) << 5) | ((t) & 31))      // r = j5..10
#define J_F(t, r)  (((r) & 3) | ((t) << 2) | (((r) >> 2) << 10))       // r = {j0,j1,j10..13}
#define J_V(t, r)  (((t) & 127) | ((r) << 7) | (((t) >> 7) << 13))     // r = j7..12

// all (write,read) lane-patterns below verified <=2 lanes/bank under SWZ
#define TRANSITION(JW, JR)                                   \
  do {                                                       \
    _Pragma("unroll")                                        \
    for (int r = 0; r < 64; ++r) tile[SWZ(JW(t, r))] = v[r]; \
    __syncthreads();                                         \
    _Pragma("unroll")                                        \
    for (int r = 0; r < 64; ++r) v[r] = tile[SWZ(JR(t, r))]; \
    __syncthreads();                                         \
  } while (0)

// ---------------- Pass 1: init + 24 gates on bits 0..13 (wires 10..23) -------
__global__ __launch_bounds__(256) void k_pass1(
    const float* __restrict__ states, const float* __restrict__ gates,
    float* __restrict__ out) {
  __shared__ float tile[16384];
  __shared__ float sLo[256];
  __shared__ float sHi[64];
  const int t = threadIdx.x;
  const int b = blockIdx.x;  // global bits 14..23 (wires 9..0)

  {
    float p = 1.f;
    for (int k = 0; k < 8; ++k) p *= states[(23 - k) * 2 + ((t >> k) & 1)];
    sLo[t] = p;
    if (t < 64) {
      float q = 1.f;
      for (int k = 0; k < 6; ++k) q *= states[(15 - k) * 2 + ((t >> k) & 1)];
      sHi[t] = q;
    }
  }
  float pref = 1.f;
  for (int k = 0; k < 10; ++k) pref *= states[(9 - k) * 2 + ((b >> k) & 1)];
  __syncthreads();

  float v[64];
  const float plT = pref * sLo[t];
#pragma unroll
  for (int r = 0; r < 64; ++r) v[r] = plT * sHi[r];  // B layout

  // Phase B (regs j8..13)
  gate_regs<4>(v, gates + 16 * 5);
  gate_regs<2>(v, gates + 16 * 6);
  gate_regs<0>(v, gates + 16 * 7);
  gate_regs<3>(v, gates + 16 * 17);
  gate_regs<1>(v, gates + 16 * 18);
  gate_regs<2>(v, gates + 16 * 29);
  TRANSITION(J_B, J_M);
  // Phase M (regs j4..9)
  gate_regs<2>(v, gates + 16 * 8);
  gate_regs<0>(v, gates + 16 * 9);
  gate_regs<3>(v, gates + 16 * 19);
  gate_regs<1>(v, gates + 16 * 20);
  gate_regs<4>(v, gates + 16 * 30);
  gate_regs<2>(v, gates + 16 * 31);
  TRANSITION(J_M, J_A);
  // Phase A (regs j0..5)
  gate_regs<2>(v, gates + 16 * 10);
  gate_regs<0>(v, gates + 16 * 11);
  gate_regs<3>(v, gates + 16 * 21);
  gate_regs<1>(v, gates + 16 * 22);
  gate_regs<4>(v, gates + 16 * 32);
  gate_regs<2>(v, gates + 16 * 33);
  gate_regs<0>(v, gates + 16 * 34);
  gate_regs<3>(v, gates + 16 * 44);
  gate_regs<1>(v, gates + 16 * 45);
  TRANSITION(J_A, J_W);
  // Phase W (regs j5..10)
  gate_regs<4>(v, gates + 16 * 41);
  gate_regs<2>(v, gates + 16 * 42);
  gate_regs<0>(v, gates + 16 * 43);
  TRANSITION(J_W, J_F);

  // float4 store: 1KB contiguous per wave-instruction
  const long long ob = ((long long)b) << 14;
#pragma unroll
  for (int c = 0; c < 16; ++c) {
    float4 w = make_float4(v[4 * c], v[4 * c + 1], v[4 * c + 2], v[4 * c + 3]);
    *(float4*)(&out[ob + (t << 2) + ((long long)c << 10)]) = w;
  }
}

// ---------------- Pass 2a: 8 gates, tile = global {0..5} u {10..17} ----------
// local j: j0..5 = global 0..5, j6..13 = global 10..17
__global__ __launch_bounds__(256) void k_pass2a(
    const float* __restrict__ gates, float* __restrict__ out) {
  __shared__ float tile[16384];
  const int t = threadIdx.x;
  const int b = blockIdx.x;
  const long long base0 = (((long long)(b >> 4)) << 18) | ((long long)(b & 15) << 6);

  float v[64];
  // load in F layout: addr = base0 + (t&15)*4 + (t>>4)*1024 + c*16384
#pragma unroll
  for (int c = 0; c < 16; ++c) {
    float4 x = *(const float4*)(&out[base0 + ((t & 15) << 2) + ((t >> 4) << 10) + ((long long)c << 14)]);
    v[4 * c] = x.x; v[4 * c + 1] = x.y; v[4 * c + 2] = x.z; v[4 * c + 3] = x.w;
  }
  // Phase F (regs {j0,j1,j10..13}): g3 local bits (12,13) -> A=4
  gate_regs<4>(v, gates + 16 * 3);
  TRANSITION(J_F, J_V);
  // Phase V (regs j7..12): local q = p1_local - 7
  gate_regs<3>(v, gates + 16 * 4);   // g4  (10,11)
  gate_regs<4>(v, gates + 16 * 15);  // g15 (11,12)
  gate_regs<2>(v, gates + 16 * 16);  // g16 (9,10)
  gate_regs<3>(v, gates + 16 * 27);  // g27 (10,11)
  gate_regs<1>(v, gates + 16 * 28);  // g28 (8,9)
  gate_regs<2>(v, gates + 16 * 39);  // g39 (9,10)
  gate_regs<0>(v, gates + 16 * 40);  // g40 (7,8)
  TRANSITION(J_V, J_F);

#pragma unroll
  for (int c = 0; c < 16; ++c) {
    float4 w = make_float4(v[4 * c], v[4 * c + 1], v[4 * c + 2], v[4 * c + 3]);
    *(float4*)(&out[base0 + ((t & 15) << 2) + ((t >> 4) << 10) + ((long long)c << 14)]) = w;
  }
}

// ---------------- Pass 2b: 14 gates, tile = global {0..4} u {15..23} ---------
// local j: j0..4 = global 0..4, j5..13 = global 15..23
__global__ __launch_bounds__(256) void k_pass2b(
    const float* __restrict__ gates, float* __restrict__ out) {
  __shared__ float tile[16384];
  const int t = threadIdx.x;
  const int b = blockIdx.x;  // global bits 5..14

  float v[64];
  // load in F layout: addr = (t&7)*4 + b*32 + (t>>3)*32768 + c*1048576
#pragma unroll
  for (int c = 0; c < 16; ++c) {
    float4 x = *(const float4*)(&out[((t & 7) << 2) + ((long long)b << 5) + ((t >> 3) << 15) + ((long long)c << 20)]);
    v[4 * c] = x.x; v[4 * c + 1] = x.y; v[4 * c + 2] = x.z; v[4 * c + 3] = x.w;
  }
  // Phase F (regs {j0,j1,j10..13}): gates with both local bits in 10..13
  gate_regs<4>(v, gates + 16 * 0);   // g0  (12,13) -> A = jlow-8 on F's j10..13 = r2..5: (12,13)->A=4
  gate_regs<2>(v, gates + 16 * 1);   // g1  (10,11)
  gate_regs<3>(v, gates + 16 * 12);  // g12 (11,12)
  gate_regs<4>(v, gates + 16 * 23);  // g23 (12,13)
  TRANSITION(J_F, J_B);
  // Phase B (regs j8..13): A = p1_local - 8
  gate_regs<0>(v, gates + 16 * 2);   // g2  (8,9)
  gate_regs<1>(v, gates + 16 * 13);  // g13 (9,10)
  gate_regs<2>(v, gates + 16 * 24);  // g24 (10,11)
  gate_regs<3>(v, gates + 16 * 35);  // g35 (11,12)
  TRANSITION(J_B, J_W);
  // Phase W (regs j5..10): A = p1_local - 5
  gate_regs<2>(v, gates + 16 * 14);  // g14 (7,8)
  gate_regs<3>(v, gates + 16 * 25);  // g25 (8,9)
  gate_regs<1>(v, gates + 16 * 26);  // g26 (6,7)
  gate_regs<4>(v, gates + 16 * 36);  // g36 (9,10)
  gate_regs<2>(v, gates + 16 * 37);  // g37 (7,8)
  gate_regs<0>(v, gates + 16 * 38);  // g38 (5,6)
  TRANSITION(J_W, J_F);

#pragma unroll
  for (int c = 0; c < 16; ++c) {
    float4 w = make_float4(v[4 * c], v[4 * c + 1], v[4 * c + 2], v[4 * c + 3]);
    *(float4*)(&out[((t & 7) << 2) + ((long long)b << 5) + ((t >> 3) << 15) + ((long long)c << 20)]) = w;
  }
}

extern "C" void kernel_launch(void* const* d_in, const int* in_sizes, int n_in,
                              void* d_out, int out_size, void* d_ws, size_t ws_size,
                              hipStream_t stream) {
  const float* states = (const float*)d_in[0];  // (24, 2) f32
  const float* gates = (const float*)d_in[1];   // (46, 2,2,2,2) f32
  float* out = (float*)d_out;                   // 2^24 f32

  k_pass1<<<1024, 256, 0, stream>>>(states, gates, out);
  k_pass2a<<<1024, 256, 0, stream>>>(gates, out);
  k_pass2b<<<1024, 256, 0, stream>>>(gates, out);
}